// Round 3
// baseline (157.113 us; speedup 1.0000x reference)
//
#include <hip/hip_runtime.h>
#include <hip/hip_bf16.h>
#include <stdint.h>
#include <stddef.h>

#define BATCH 4096
#define INF   1024
#define OUTF  1024
#define KDIM  8192            // 1024 in-features * 8 spline bases
#define KS    4               // split-K factor
#define KSL   (KDIM / KS)     // 2048 per slice
#define NTK   (KSL / 32)      // 64 K-tiles (BK=32) per block

typedef __attribute__((ext_vector_type(8))) short  short8;
typedef __attribute__((ext_vector_type(4))) float  f32x4;

__device__ constexpr float knot(int j) { return (float)(j - 3) * 0.4f - 1.0f; }

// ---------------------------------------------------------------------------
// Kernel 1: B-spline bases (HBM-bound, ~6 TB/s). One thread per (b,i).
// ---------------------------------------------------------------------------
__global__ __launch_bounds__(256) void kan_bases(const float* __restrict__ x,
                                                 short8* __restrict__ A) {
    size_t idx = (size_t)blockIdx.x * 256 + threadIdx.x;
    float xv = x[idx];

    float b[11];
#pragma unroll
    for (int j = 0; j < 11; ++j)
        b[j] = (xv >= knot(j) && xv < knot(j + 1)) ? 1.0f : 0.0f;

#pragma unroll
    for (int k = 1; k <= 3; ++k) {
#pragma unroll
        for (int j = 0; j + k < 11; ++j) {
            float left  = (xv - knot(j))         * (1.0f / (knot(j + k)     - knot(j)));
            float right = (knot(j + k + 1) - xv) * (1.0f / (knot(j + k + 1) - knot(j + 1)));
            b[j] = left * b[j] + right * b[j + 1];
        }
    }

    union { short8 v; unsigned short u[8]; } pk;
#pragma unroll
    for (int g = 0; g < 8; ++g) {
        __hip_bfloat16 h = __float2bfloat16(b[g]);
        pk.u[g] = *reinterpret_cast<unsigned short*>(&h);
    }
    A[idx] = pk.v;
}

// ---------------------------------------------------------------------------
// Kernel 2: weight fp32 -> bf16 (B^T row-major over k = i*8+g already).
// ---------------------------------------------------------------------------
__global__ __launch_bounds__(256) void kan_wconv(const f32x4* __restrict__ w,
                                                 short8* __restrict__ Wb) {
    size_t idx = (size_t)blockIdx.x * 256 + threadIdx.x;
    f32x4 a = w[idx * 2];
    f32x4 c = w[idx * 2 + 1];
    float t[8] = {a[0], a[1], a[2], a[3], c[0], c[1], c[2], c[3]};
    union { short8 v; unsigned short u[8]; } pk;
#pragma unroll
    for (int g = 0; g < 8; ++g) {
        __hip_bfloat16 h = __float2bfloat16(t[g]);
        pk.u[g] = *reinterpret_cast<unsigned short*>(&h);
    }
    Wb[idx] = pk.v;
}

// ---------------------------------------------------------------------------
// Kernel 3: bf16 GEMM, 256x256 tile, split-K=4, deep pipeline.
// 512 threads = 8 waves (2M x 4N), per-wave 128x64, BK=32.
// Ring of 4 LDS K-tile buffers; prefetch depth 3; counted vmcnt(8) per iter.
// ---------------------------------------------------------------------------
__device__ __forceinline__ void gload16(const void* g, void* l) {
    __builtin_amdgcn_global_load_lds((const __attribute__((address_space(1))) void*)g,
                                     (__attribute__((address_space(3))) void*)l,
                                     16, 0, 0);
}

__global__ __launch_bounds__(512, 2) void kan_gemm(const __hip_bfloat16* __restrict__ A,
                                                   const __hip_bfloat16* __restrict__ Bt,
                                                   float* __restrict__ C) {
    // ring: 4 slots, each one K-tile: A 256x32 + B 256x32 bf16 = 32 KiB -> 128 KiB
    __shared__ __hip_bfloat16 sA[4][256 * 32];
    __shared__ __hip_bfloat16 sB[4][256 * 32];

    const int tid = threadIdx.x;

    // bijective XCD chunk swizzle: nwg=256, 8 XCDs, 32 blocks each.
    const int orig = blockIdx.x;
    const int sb   = (orig & 7) * 32 + (orig >> 3);
    const int bm   = sb >> 4;          // 0..15
    const int bn   = (sb >> 2) & 3;    // 0..3
    const int ks   = sb & 3;           // 0..3
    const int m0   = bm << 8;
    const int n0   = bn << 8;
    const int k0   = ks * KSL;

    // --- staging geometry: per K-tile, per thread: A r=0,1 + B r=0,1 (4x16B) ---
    // LDS linear: thread t, load r -> elem (r*4096 + t*8) = row (r*128 + t>>2), slot t&3.
    // XOR swizzle: LDS[row][slot] holds source slot (slot ^ ((row>>1)&3)); here
    // (row>>1)&3 == (t>>3)&3 for both r (t+512 preserves it).
    const int srow = tid >> 2;                                // 0..127
    const int scol = ((tid & 3) ^ ((tid >> 3) & 3)) << 3;     // src elem col
    const __hip_bfloat16* gA = A  + (size_t)(m0 + srow) * KDIM + k0 + scol;
    const __hip_bfloat16* gB = Bt + (size_t)(n0 + srow) * KDIM + k0 + scol;
    const int ldst = tid * 8;                                 // + r*4096 elems

#define STAGE_A(kt) do { int _s = (kt) & 3;                                        \
        gload16(gA + (size_t)(kt) * 32,                       &sA[_s][ldst]);       \
        gload16(gA + (size_t)128 * KDIM + (size_t)(kt) * 32,  &sA[_s][ldst + 4096]);\
    } while (0)
#define STAGE_B(kt) do { int _s = (kt) & 3;                                        \
        gload16(gB + (size_t)(kt) * 32,                       &sB[_s][ldst]);       \
        gload16(gB + (size_t)128 * KDIM + (size_t)(kt) * 32,  &sB[_s][ldst + 4096]);\
    } while (0)

    // --- compute geometry: wave w -> rows [wr*128,+128), cols [wc*64,+64) ---
    const int w    = tid >> 6;
    const int lane = tid & 63;
    const int wr   = (w >> 2) & 1;
    const int wc   = w & 3;
    const int lr   = lane & 15;
    const int lk   = lane >> 4;                               // 0..3
    const int kx   = (lk ^ ((lr >> 1) & 3)) << 3;             // swizzled k elem off
    const int arow = wr * 128 + lr;                           // + fi*16
    const int brow = wc * 64 + lr;                            // + fj*16

    f32x4 acc[8][4];
#pragma unroll
    for (int i = 0; i < 8; ++i)
#pragma unroll
        for (int j = 0; j < 4; ++j)
            acc[i][j] = (f32x4){0.0f, 0.0f, 0.0f, 0.0f};

    // --- prologue: stage K-tiles 0,1,2 (12 loads); wait oldest 4 (tile 0) ---
    STAGE_A(0); STAGE_B(0);
    STAGE_A(1); STAGE_B(1);
    STAGE_A(2); STAGE_B(2);
    asm volatile("s_waitcnt vmcnt(8)" ::: "memory");
    __builtin_amdgcn_s_barrier();
    __builtin_amdgcn_sched_barrier(0);

    for (int t = 0; t < NTK; ++t) {
        const __hip_bfloat16* tA = &sA[t & 3][0];
        const __hip_bfloat16* tB = &sB[t & 3][0];
        const bool pf = (t + 3) < NTK;

        // ---- phase 0: stage A(t+3) | read A-frags + B(0,1) | 16 MFMA ----
        if (pf) STAGE_A(t + 3);
        short8 af[8];
#pragma unroll
        for (int fi = 0; fi < 8; ++fi)
            af[fi] = *reinterpret_cast<const short8*>(tA + (arow + fi * 16) * 32 + kx);
        short8 bf0 = *reinterpret_cast<const short8*>(tB + (brow     ) * 32 + kx);
        short8 bf1 = *reinterpret_cast<const short8*>(tB + (brow + 16) * 32 + kx);
        __builtin_amdgcn_s_setprio(1);
#pragma unroll
        for (int fi = 0; fi < 8; ++fi) {
            acc[fi][0] = __builtin_amdgcn_mfma_f32_16x16x32_bf16(af[fi], bf0, acc[fi][0], 0, 0, 0);
            acc[fi][1] = __builtin_amdgcn_mfma_f32_16x16x32_bf16(af[fi], bf1, acc[fi][1], 0, 0, 0);
        }
        __builtin_amdgcn_s_setprio(0);

        // ---- phase 1: stage B(t+3) | read B(2,3) | 16 MFMA ----
        if (pf) STAGE_B(t + 3);
        short8 bf2 = *reinterpret_cast<const short8*>(tB + (brow + 32) * 32 + kx);
        short8 bf3 = *reinterpret_cast<const short8*>(tB + (brow + 48) * 32 + kx);
        __builtin_amdgcn_s_setprio(1);
#pragma unroll
        for (int fi = 0; fi < 8; ++fi) {
            acc[fi][2] = __builtin_amdgcn_mfma_f32_16x16x32_bf16(af[fi], bf2, acc[fi][2], 0, 0, 0);
            acc[fi][3] = __builtin_amdgcn_mfma_f32_16x16x32_bf16(af[fi], bf3, acc[fi][3], 0, 0, 0);
        }
        __builtin_amdgcn_s_setprio(0);

        // ---- iter end: counted wait (next tile landed; 2 tiles stay in flight) ----
        const int rem = NTK - 2 - t;         // K-tiles legitimately still in flight
        if (rem >= 2)      asm volatile("s_waitcnt vmcnt(8)" ::: "memory");
        else if (rem == 1) asm volatile("s_waitcnt vmcnt(4)" ::: "memory");
        else               asm volatile("s_waitcnt vmcnt(0)" ::: "memory");
        __builtin_amdgcn_s_barrier();
        __builtin_amdgcn_sched_barrier(0);
    }
#undef STAGE_A
#undef STAGE_B

    // --- epilogue: C/D layout col = lane&15, row = (lane>>4)*4 + reg; split-K atomics ---
#pragma unroll
    for (int fi = 0; fi < 8; ++fi) {
#pragma unroll
        for (int fj = 0; fj < 4; ++fj) {
            float* cp = C + (size_t)(m0 + wr * 128 + fi * 16 + lk * 4) * OUTF
                          + (n0 + wc * 64 + fj * 16 + lr);
#pragma unroll
            for (int r = 0; r < 4; ++r)
                atomicAdd(cp + (size_t)r * OUTF, acc[fi][fj][r]);
        }
    }
}

// ---------------------------------------------------------------------------
extern "C" void kernel_launch(void* const* d_in, const int* in_sizes, int n_in,
                              void* d_out, int out_size, void* d_ws, size_t ws_size,
                              hipStream_t stream) {
    const float* x = (const float*)d_in[0];       // (4096, 1024) fp32
    const float* w = (const float*)d_in[1];       // (1024, 1024, 8) fp32
    float* out = (float*)d_out;                   // (4096, 1024) fp32

    __hip_bfloat16* Abf = (__hip_bfloat16*)d_ws;                                     // 64 MiB
    __hip_bfloat16* Wbf = (__hip_bfloat16*)((char*)d_ws + (size_t)BATCH * KDIM * 2); // +16 MiB

    kan_bases<<<(BATCH * INF) / 256, 256, 0, stream>>>(x, (short8*)Abf);
    kan_wconv<<<(OUTF * KDIM / 8) / 256, 256, 0, stream>>>((const f32x4*)w, (short8*)Wbf);
    hipMemsetAsync(out, 0, (size_t)BATCH * OUTF * sizeof(float), stream);
    kan_gemm<<<(BATCH / 256) * (OUTF / 256) * KS, 512, 0, stream>>>(Abf, Wbf, out);
}

// Round 4
// 125.602 us; speedup vs baseline: 1.2509x; 1.2509x over previous
//
#include <hip/hip_runtime.h>
#include <hip/hip_bf16.h>
#include <stdint.h>
#include <stddef.h>

#define BATCH 4096
#define INF   1024
#define OUTF  1024
#define KDIM  8192            // 1024 in-features * 8 spline bases
#define KS    2               // split-K factor
#define KSL   (KDIM / KS)     // 4096 per slice
#define NT    (KSL / 64)      // 64 K-tiles of BK=64

typedef __attribute__((ext_vector_type(8))) short  short8;
typedef __attribute__((ext_vector_type(4))) float  f32x4;

__device__ constexpr float knot(int j) { return (float)(j - 3) * 0.4f - 1.0f; }

// ---------------------------------------------------------------------------
// Kernel 1: B-spline bases. One thread per (b,i); writes 8 bf16 (16 B).
// ---------------------------------------------------------------------------
__global__ __launch_bounds__(256) void kan_bases(const float* __restrict__ x,
                                                 short8* __restrict__ A) {
    size_t idx = (size_t)blockIdx.x * 256 + threadIdx.x;
    float xv = x[idx];

    float b[11];
#pragma unroll
    for (int j = 0; j < 11; ++j)
        b[j] = (xv >= knot(j) && xv < knot(j + 1)) ? 1.0f : 0.0f;

#pragma unroll
    for (int k = 1; k <= 3; ++k) {
#pragma unroll
        for (int j = 0; j + k < 11; ++j) {
            float left  = (xv - knot(j))         * (1.0f / (knot(j + k)     - knot(j)));
            float right = (knot(j + k + 1) - xv) * (1.0f / (knot(j + k + 1) - knot(j + 1)));
            b[j] = left * b[j] + right * b[j + 1];
        }
    }

    union { short8 v; unsigned short u[8]; } pk;
#pragma unroll
    for (int g = 0; g < 8; ++g) {
        __hip_bfloat16 h = __float2bfloat16(b[g]);
        pk.u[g] = *reinterpret_cast<unsigned short*>(&h);
    }
    A[idx] = pk.v;
}

// ---------------------------------------------------------------------------
// Kernel 2: weight fp32 -> bf16 (B^T row-major over k = i*8+g already).
// ---------------------------------------------------------------------------
__global__ __launch_bounds__(256) void kan_wconv(const f32x4* __restrict__ w,
                                                 short8* __restrict__ Wb) {
    size_t idx = (size_t)blockIdx.x * 256 + threadIdx.x;
    f32x4 a = w[idx * 2];
    f32x4 c = w[idx * 2 + 1];
    float t[8] = {a[0], a[1], a[2], a[3], c[0], c[1], c[2], c[3]};
    union { short8 v; unsigned short u[8]; } pk;
#pragma unroll
    for (int g = 0; g < 8; ++g) {
        __hip_bfloat16 h = __float2bfloat16(t[g]);
        pk.u[g] = *reinterpret_cast<unsigned short*>(&h);
    }
    Wb[idx] = pk.v;
}

// ---------------------------------------------------------------------------
// Kernel 3: bf16 GEMM, 256x128 tile, BK=64, split-K=2, ring-3 LDS (144 KiB),
// 512 threads = 8 waves (4M x 2N, 64x64 per wave), 4 fine phases per K-tile,
// counted vmcnt(6) per iter (never 0 until tail). XOR swizzle byte^((row&7)<<4)
// applied to gload SOURCE col and ds_read col (involution, both sides).
// ---------------------------------------------------------------------------
__device__ __forceinline__ void gload16(const void* g, void* l) {
    __builtin_amdgcn_global_load_lds((const __attribute__((address_space(1))) void*)g,
                                     (__attribute__((address_space(3))) void*)l,
                                     16, 0, 0);
}

#define MFMA(a, b, c) __builtin_amdgcn_mfma_f32_16x16x32_bf16((a), (b), (c), 0, 0, 0)

__global__ __launch_bounds__(512, 2) void kan_gemm(const __hip_bfloat16* __restrict__ A,
                                                   const __hip_bfloat16* __restrict__ Bt,
                                                   float* __restrict__ C) {
    __shared__ __hip_bfloat16 sA[3][256 * 64];   // 96 KiB
    __shared__ __hip_bfloat16 sB[3][128 * 64];   // 48 KiB

    const int tid  = threadIdx.x;
    const int orig = blockIdx.x;
    const int sb   = (orig & 7) * 32 + (orig >> 3);   // XCD chunk swizzle (256%8==0)
    const int bm   = sb >> 4;            // 0..15
    const int bn   = (sb >> 1) & 7;      // 0..7
    const int ksl  = sb & 1;             // 0..1
    const int m0   = bm << 8;
    const int n0   = bn << 7;
    const int k0   = ksl * KSL;

    // staging: thread t -> LDS row (t>>3)+r*64, 16B slot (t&7) (linear dest).
    // source col pre-swizzled: LDS[row][slot] = G[row][slot ^ (row&7)].
    const int srow = tid >> 3;                                // 0..63
    const int scol = (((tid & 7) ^ (srow & 7)) << 3);         // elems
    const __hip_bfloat16* gA = A  + (size_t)(m0 + srow) * KDIM + k0 + scol;
    const __hip_bfloat16* gB = Bt + (size_t)(n0 + srow) * KDIM + k0 + scol;
    const int ldst = tid * 8;                                 // + r*4096 elems

#define GLA(slot, kt, r) gload16(gA + (size_t)(kt) * 64 + (size_t)((r) * 64) * KDIM, \
                                 &sA[slot][(r) * 4096 + ldst])
#define GLB(slot, kt, r) gload16(gB + (size_t)(kt) * 64 + (size_t)((r) * 64) * KDIM, \
                                 &sB[slot][(r) * 4096 + ldst])

    // compute: wave w -> rows [wr*64,+64), cols [wc*64,+64) of the 256x128 tile
    const int w    = tid >> 6;
    const int lane = tid & 63;
    const int wr   = w >> 1;             // 0..3
    const int wc   = w & 1;              // 0..1
    const int lr   = lane & 15;
    const int lk   = lane >> 4;          // 0..3
    const int kx0  = (lk ^ (lr & 7)) << 3;     // kk=0 swizzled elem col; kk=1 = kx0^32
    const int ar0  = (wr << 6) + lr;     // + fih*32 + fi'*16
    const int br0  = (wc << 6) + lr;     // + fjh*32 + fj'*16

    f32x4 acc[4][4];
#pragma unroll
    for (int i = 0; i < 4; ++i)
#pragma unroll
        for (int j = 0; j < 4; ++j)
            acc[i][j] = (f32x4){0.0f, 0.0f, 0.0f, 0.0f};

    // --- prologue: stage tiles 0 and 1 (6 loads each); wait tile 0 landed ---
    GLA(0, 0, 0); GLA(0, 0, 1); GLA(0, 0, 2); GLA(0, 0, 3); GLB(0, 0, 0); GLB(0, 0, 1);
    GLA(1, 1, 0); GLA(1, 1, 1); GLA(1, 1, 2); GLA(1, 1, 3); GLB(1, 1, 0); GLB(1, 1, 1);
    asm volatile("s_waitcnt vmcnt(6)" ::: "memory");
    __builtin_amdgcn_s_barrier();

    int s = 0;
#pragma unroll 1
    for (int t = 0; t < NT; ++t) {
        const __hip_bfloat16* tA = &sA[s][0];
        const __hip_bfloat16* tB = &sB[s][0];
        const int  s2 = (s >= 1) ? s - 1 : 2;    // (s+2)%3
        const bool pf = (t + 2) < NT;

        short8 af[2][2], b0[2][2], b1[2][2];

        // ---- phase 0: read A-lo + B-lo frags | stage A r0,r1 | MFMA q(0,0) ----
#pragma unroll
        for (int fi = 0; fi < 2; ++fi) {
            af[fi][0] = *reinterpret_cast<const short8*>(tA + (ar0 + fi * 16) * 64 + kx0);
            af[fi][1] = *reinterpret_cast<const short8*>(tA + (ar0 + fi * 16) * 64 + (kx0 ^ 32));
        }
#pragma unroll
        for (int fj = 0; fj < 2; ++fj) {
            b0[fj][0] = *reinterpret_cast<const short8*>(tB + (br0 + fj * 16) * 64 + kx0);
            b0[fj][1] = *reinterpret_cast<const short8*>(tB + (br0 + fj * 16) * 64 + (kx0 ^ 32));
        }
        if (pf) { GLA(s2, t + 2, 0); GLA(s2, t + 2, 1); }
        __builtin_amdgcn_s_barrier();
        asm volatile("s_waitcnt lgkmcnt(0)" ::: "memory");
        __builtin_amdgcn_s_setprio(1);
#pragma unroll
        for (int kk = 0; kk < 2; ++kk)
#pragma unroll
            for (int fi = 0; fi < 2; ++fi)
#pragma unroll
                for (int fj = 0; fj < 2; ++fj)
                    acc[fi][fj] = MFMA(af[fi][kk], b0[fj][kk], acc[fi][fj]);
        __builtin_amdgcn_s_setprio(0);
        __builtin_amdgcn_s_barrier();

        // ---- phase 1: read B-hi frags | stage A r2,r3 | MFMA q(0,1) ----
#pragma unroll
        for (int fj = 0; fj < 2; ++fj) {
            b1[fj][0] = *reinterpret_cast<const short8*>(tB + (br0 + 32 + fj * 16) * 64 + kx0);
            b1[fj][1] = *reinterpret_cast<const short8*>(tB + (br0 + 32 + fj * 16) * 64 + (kx0 ^ 32));
        }
        if (pf) { GLA(s2, t + 2, 2); GLA(s2, t + 2, 3); }
        __builtin_amdgcn_s_barrier();
        asm volatile("s_waitcnt lgkmcnt(0)" ::: "memory");
        __builtin_amdgcn_s_setprio(1);
#pragma unroll
        for (int kk = 0; kk < 2; ++kk)
#pragma unroll
            for (int fi = 0; fi < 2; ++fi)
#pragma unroll
                for (int fj = 0; fj < 2; ++fj)
                    acc[fi][2 + fj] = MFMA(af[fi][kk], b1[fj][kk], acc[fi][2 + fj]);
        __builtin_amdgcn_s_setprio(0);
        __builtin_amdgcn_s_barrier();

        // ---- phase 2: read A-hi frags | stage B r0,r1 | MFMA q(1,0) ----
#pragma unroll
        for (int fi = 0; fi < 2; ++fi) {
            af[fi][0] = *reinterpret_cast<const short8*>(tA + (ar0 + 32 + fi * 16) * 64 + kx0);
            af[fi][1] = *reinterpret_cast<const short8*>(tA + (ar0 + 32 + fi * 16) * 64 + (kx0 ^ 32));
        }
        if (pf) { GLB(s2, t + 2, 0); GLB(s2, t + 2, 1); }
        __builtin_amdgcn_s_barrier();
        asm volatile("s_waitcnt lgkmcnt(0)" ::: "memory");
        __builtin_amdgcn_s_setprio(1);
#pragma unroll
        for (int kk = 0; kk < 2; ++kk)
#pragma unroll
            for (int fi = 0; fi < 2; ++fi)
#pragma unroll
                for (int fj = 0; fj < 2; ++fj)
                    acc[2 + fi][fj] = MFMA(af[fi][kk], b0[fj][kk], acc[2 + fi][fj]);
        __builtin_amdgcn_s_setprio(0);
        __builtin_amdgcn_s_barrier();

        // ---- phase 3: MFMA q(1,1) | counted vmcnt (tile t+1 landed) ----
        __builtin_amdgcn_s_setprio(1);
#pragma unroll
        for (int kk = 0; kk < 2; ++kk)
#pragma unroll
            for (int fi = 0; fi < 2; ++fi)
#pragma unroll
                for (int fj = 0; fj < 2; ++fj)
                    acc[2 + fi][2 + fj] = MFMA(af[fi][kk], b1[fj][kk], acc[2 + fi][2 + fj]);
        __builtin_amdgcn_s_setprio(0);
        if (pf) asm volatile("s_waitcnt vmcnt(6)" ::: "memory");
        else    asm volatile("s_waitcnt vmcnt(0)" ::: "memory");
        __builtin_amdgcn_s_barrier();

        s = (s == 2) ? 0 : s + 1;
    }
#undef GLA
#undef GLB

    // --- epilogue: C/D layout col = lane&15, row = (lane>>4)*4 + reg; split-K atomics ---
#pragma unroll
    for (int fi = 0; fi < 4; ++fi) {
#pragma unroll
        for (int fj = 0; fj < 4; ++fj) {
            float* cp = C + (size_t)(m0 + (wr << 6) + fi * 16 + lk * 4) * OUTF
                          + (n0 + (wc << 6) + fj * 16 + lr);
#pragma unroll
            for (int r = 0; r < 4; ++r)
                atomicAdd(cp + (size_t)r * OUTF, acc[fi][fj][r]);
        }
    }
}

// ---------------------------------------------------------------------------
extern "C" void kernel_launch(void* const* d_in, const int* in_sizes, int n_in,
                              void* d_out, int out_size, void* d_ws, size_t ws_size,
                              hipStream_t stream) {
    const float* x = (const float*)d_in[0];       // (4096, 1024) fp32
    const float* w = (const float*)d_in[1];       // (1024, 1024, 8) fp32
    float* out = (float*)d_out;                   // (4096, 1024) fp32

    __hip_bfloat16* Abf = (__hip_bfloat16*)d_ws;                                     // 64 MiB
    __hip_bfloat16* Wbf = (__hip_bfloat16*)((char*)d_ws + (size_t)BATCH * KDIM * 2); // +16 MiB

    kan_bases<<<(BATCH * INF) / 256, 256, 0, stream>>>(x, (short8*)Abf);
    kan_wconv<<<(OUTF * KDIM / 8) / 256, 256, 0, stream>>>((const f32x4*)w, (short8*)Wbf);
    hipMemsetAsync(out, 0, (size_t)BATCH * OUTF * sizeof(float), stream);
    kan_gemm<<<(BATCH / 256) * (OUTF / 128) * KS, 512, 0, stream>>>(Abf, Wbf, out);
}